// Round 9
// baseline (261.831 us; speedup 1.0000x reference)
//
#include <hip/hip_runtime.h>
#include <hip/hip_bf16.h>

// B=4, L=S=1024, D=1024, H=16, HD=64. Inputs fp32, output fp32, mask bool-ish
// (runtime-classified). R7: 241us (proj 56us, 3.1e6 conflicts). R8: BK=64
// regressed proj to 68us (duration == hbm_bytes/BW; staging-concurrency-bound
// — m132's lesson). R9: BK=32 (R7 memory behavior) + fragment-ordered GLD
// staging (conflict-free ds_read_b128, same 16row x 64B per-GLD coalescing).

typedef __bf16 bf16;
typedef __bf16 bf16x8 __attribute__((ext_vector_type(8)));
typedef float floatx4 __attribute__((ext_vector_type(4)));

#define D_MODEL 1024
#define NHEAD   16
#define HDIM    64
#define BATCH   4
#define SEQ     1024
#define M_ROWS  (BATCH * SEQ)         // 4096
#define ACT_N   ((size_t)M_ROWS * D_MODEL)    // 4M
#define W_N     ((size_t)D_MODEL * D_MODEL)   // 1M
#define SC2     0.18033688011112042f  // 0.125 * log2(e)

#define GLD(gp, lp) __builtin_amdgcn_global_load_lds( \
    (__attribute__((address_space(1))) void*)(gp), \
    (__attribute__((address_space(3))) void*)(lp), 16, 0, 0)

// ---------------------------------------------------------------------------
// Fused convert + mask. Blocks 0..8191: fp32->bf16 of q,k,v,Wq,Wk,Wv,Wo into
// one contiguous bf16 region (8 elems/thread). Block 8192: classify mask
// dtype (int32/byte/bf16/fp32) and emit float bias 0 / -1e30.
// ---------------------------------------------------------------------------
__global__ __launch_bounds__(256)
void k_convert_all(const float* __restrict__ a0, const float* __restrict__ a1,
                   const float* __restrict__ a2,
                   const float* __restrict__ w0, const float* __restrict__ w1,
                   const float* __restrict__ w2, const float* __restrict__ w3,
                   bf16* __restrict__ dst,
                   const unsigned* __restrict__ m, float* __restrict__ mbias)
{
    if (blockIdx.x == 8192) {
        __shared__ unsigned viol[4];
        __shared__ int fmsh;
        if (threadIdx.x < 4) viol[threadIdx.x] = 0;
        __syncthreads();
        unsigned a = 0, b = 0, c = 0, d = 0;
        for (int i = threadIdx.x; i < 1024; i += 256) {
            unsigned v = m[i];
            if (v > 1u) a = 1;
            if (((v & 0xFFu) > 1u) || (((v >> 8) & 0xFFu) > 1u) ||
                (((v >> 16) & 0xFFu) > 1u) || (((v >> 24) & 0xFFu) > 1u)) b = 1;
            unsigned lo = v & 0xFFFFu, hi = v >> 16;
            if (!((lo == 0u || lo == 0x3F80u) && (hi == 0u || hi == 0x3F80u))) c = 1;
            if (lo != 0u) d = 1;
        }
        if (a) atomicOr(&viol[0], 1u);
        if (b) atomicOr(&viol[1], 1u);
        if (c) atomicOr(&viol[2], 1u);
        if (d) atomicOr(&viol[3], 1u);
        __syncthreads();
        if (threadIdx.x == 0) {
            int fm;
            if (!viol[0])      fm = 1;
            else if (!viol[1]) fm = 0;
            else if (!viol[2]) fm = viol[3] ? 2 : 3;
            else               fm = 0;
            fmsh = fm;
        }
        __syncthreads();
        const int fm = fmsh;
        for (int i = 0; i < 16; ++i) {
            int s = i * 256 + threadIdx.x;
            bool msk;
            if (fm == 1)      msk = ((const int*)m)[s] != 0;
            else if (fm == 2) msk = ((const unsigned short*)m)[s] != 0;
            else if (fm == 3) msk = ((const unsigned*)m)[s] != 0;
            else              msk = ((const unsigned char*)m)[s] != 0;
            mbias[s] = msk ? -1e30f : 0.f;
        }
        return;
    }

    size_t i = ((size_t)blockIdx.x * 256 + threadIdx.x) * 8;
    const float* src; size_t off;
    if (i < ((size_t)12 << 20)) {
        int z = (int)(i >> 22);
        src = (z == 0) ? a0 : (z == 1) ? a1 : a2;
        off = i & (((size_t)1 << 22) - 1);
    } else {
        size_t r = i - ((size_t)12 << 20);
        int j = (int)(r >> 20);
        src = (j == 0) ? w0 : (j == 1) ? w1 : (j == 2) ? w2 : w3;
        off = r & (((size_t)1 << 20) - 1);
    }
    float4 f0 = ((const float4*)(src + off))[0];
    float4 f1 = ((const float4*)(src + off))[1];
    bf16x8 o;
    o[0] = (bf16)f0.x; o[1] = (bf16)f0.y; o[2] = (bf16)f0.z; o[3] = (bf16)f0.w;
    o[4] = (bf16)f1.x; o[5] = (bf16)f1.y; o[6] = (bf16)f1.z; o[7] = (bf16)f1.w;
    *(bf16x8*)(dst + i) = o;
}

// ---------------------------------------------------------------------------
// GEMM core: C[m0..+128, n0..+128] = A@W^T + bias. BK=32, fragment-ordered
// LDS. Staging bijection per 128x32 tile (512 16B-chunks):
//   c = i*256 + t,  f = c>>6 (= i*4 + w, wave-uniform), lane = c&63;
//   row = (f>>2)*64 + (f&3)*16 + (lane&15), cb = (lane>>4)*8.
// Fragment read (half hf, tile i): LDS[(hf*4+i)*512 + lane*8] — linear in
// lane, conflict-free ds_read_b128. Per-GLD global: 16 rows x 64B (same
// coalescing as m97 row-major staging).
// ---------------------------------------------------------------------------
template<typename CT>
__device__ __forceinline__ void gemm_core(const bf16* __restrict__ A,
                                          const bf16* __restrict__ W,
                                          const float* __restrict__ bias,
                                          CT* __restrict__ C,
                                          int m0, int n0, bool rowBias)
{
    __shared__ alignas(16) bf16 As[128 * 32];
    __shared__ alignas(16) bf16 Bs[128 * 32];

    const int t    = threadIdx.x;
    const int lane = t & 63;
    const int w    = t >> 6;
    const int wm   = w >> 1, wn = w & 1;
    const int l15  = lane & 15;
    const int quad = lane >> 4;

    floatx4 acc[4][4] = {};

    for (int k0 = 0; k0 < D_MODEL; k0 += 32) {
        #pragma unroll
        for (int i = 0; i < 2; ++i) {
            int f   = i * 4 + w;
            int row = (f >> 2) * 64 + (f & 3) * 16 + l15;
            int cb  = quad * 8;
            const bf16* ga = A + (size_t)(m0 + row) * D_MODEL + k0 + cb;
            const bf16* gb = W + (size_t)(n0 + row) * D_MODEL + k0 + cb;
            int lo = (i * 256 + w * 64) * 8;   // wave-uniform base (+lane*16)
            GLD(ga, As + lo);
            GLD(gb, Bs + lo);
        }
        __syncthreads();

        bf16x8 af[4], bfr[4];
        #pragma unroll
        for (int i = 0; i < 4; ++i)
            af[i] = *(const bf16x8*)&As[(wm * 4 + i) * 512 + lane * 8];
        #pragma unroll
        for (int j = 0; j < 4; ++j)
            bfr[j] = *(const bf16x8*)&Bs[(wn * 4 + j) * 512 + lane * 8];

        #pragma unroll
        for (int i = 0; i < 4; ++i)
            #pragma unroll
            for (int j = 0; j < 4; ++j)
                acc[i][j] = __builtin_amdgcn_mfma_f32_16x16x32_bf16(
                    af[i], bfr[j], acc[i][j], 0, 0, 0);
        __syncthreads();
    }

    // epilogue: C/D layout col=lane&15, row=quad*4+r
    #pragma unroll
    for (int i = 0; i < 4; ++i) {
        int rowb = m0 + wm * 64 + i * 16 + quad * 4;
        float bvr[4];
        if (rowBias) {
            #pragma unroll
            for (int r = 0; r < 4; ++r) bvr[r] = bias[rowb + r];
        }
        #pragma unroll
        for (int j = 0; j < 4; ++j) {
            int col = n0 + wn * 64 + j * 16 + l15;
            float bc = rowBias ? 0.f : bias[col];
            #pragma unroll
            for (int r = 0; r < 4; ++r) {
                float val = acc[i][j][r] + (rowBias ? bvr[r] : bc);
                C[(size_t)(rowb + r) * D_MODEL + col] = (CT)val;
            }
        }
    }
}

// Fused projection GEMM: blocks 0..511 = Q/K proj (4096x1024), 512..767 =
// transposed V proj per batch: Vt_b = Wv @ value_b^T (+bv by row).
__global__ __launch_bounds__(256)
void k_gemm_proj(const bf16* __restrict__ cq, const bf16* __restrict__ ck,
                 const bf16* __restrict__ cv,
                 const bf16* __restrict__ cWq, const bf16* __restrict__ cWk,
                 const bf16* __restrict__ cWv,
                 const float* __restrict__ bq, const float* __restrict__ bk,
                 const float* __restrict__ bv,
                 bf16* __restrict__ qproj, bf16* __restrict__ kproj,
                 bf16* __restrict__ vt)
{
    const int bid = blockIdx.x;
    if (bid < 512) {
        int z = bid >> 8, r = bid & 255;
        int n0 = (r & 7) * 128, m0 = (r >> 3) * 128;
        gemm_core<bf16>(z ? ck : cq, z ? cWk : cWq, z ? bk : bq,
                        z ? kproj : qproj, m0, n0, false);
    } else {
        int r = bid - 512;
        int b = r >> 6, r2 = r & 63;
        int n0 = (r2 & 7) * 128, m0 = (r2 >> 3) * 128;
        gemm_core<bf16>(cWv, cv + (size_t)b * W_N, bv,
                        vt + (size_t)b * W_N, m0, n0, true);
    }
}

__global__ __launch_bounds__(256)
void k_gemm_o(const bf16* __restrict__ A, const bf16* __restrict__ W,
              const float* __restrict__ bb, float* __restrict__ C)
{
    gemm_core<float>(A, W, bb, C, blockIdx.y * 128, blockIdx.x * 128, false);
}

// ---------------------------------------------------------------------------
// Flash attention, fragment-ordered LDS. Grid (L/64, B*H), 256 thr (4 waves),
// wave = 16 q rows. No-max exp2 softmax; l via MFMA with ones-B-fragment.
// ---------------------------------------------------------------------------
__global__ __launch_bounds__(256)
void k_attn(const bf16* __restrict__ qproj, const bf16* __restrict__ kproj,
            const bf16* __restrict__ vt, const float* __restrict__ mbias_g,
            bf16* __restrict__ ctx)
{
    __shared__ alignas(16) bf16 Qst[4096];   // [w*2+kk][lane]*8, frag order
    __shared__ alignas(16) bf16 Kst[4096];   // [f=j*2+kk][lane]*8
    __shared__ alignas(16) bf16 Vst[4096];
    __shared__ alignas(16) bf16 Past[4096];  // per-wave 1024, A-frag order
    __shared__ float MB[1024];

    const int t    = threadIdx.x;
    const int lane = t & 63;
    const int w    = t >> 6;
    const int l15  = lane & 15;
    const int quad = lane >> 4;

    const int q0 = blockIdx.x * 64;
    const int b  = blockIdx.y >> 4;
    const int h  = blockIdx.y & 15;

    #pragma unroll
    for (int i = 0; i < 4; ++i)
        MB[i * 256 + t] = mbias_g[b * SEQ + i * 256 + t];

    #pragma unroll
    for (int kk = 0; kk < 2; ++kk) {
        const bf16* gp = qproj + (size_t)(b * SEQ + q0 + w * 16 + l15) * D_MODEL
                       + h * HDIM + kk * 32 + quad * 8;
        GLD(gp, Qst + (w * 2 + kk) * 512);
    }
    __syncthreads();

    bf16x8 qf[2];
    #pragma unroll
    for (int kk = 0; kk < 2; ++kk)
        qf[kk] = *(const bf16x8*)&Qst[(w * 2 + kk) * 512 + lane * 8];

    bf16x8 ones;
    #pragma unroll
    for (int e = 0; e < 8; ++e) ones[e] = (bf16)1.0f;

    floatx4 o[4] = {};
    floatx4 accl = {};

    const int pbase = w * 1024 + (l15 >> 3) * 128 + quad * 32 + (l15 & 7);

    for (int s0 = 0; s0 < SEQ; s0 += 64) {
        __syncthreads();
        #pragma unroll
        for (int i = 0; i < 2; ++i) {
            int f = w * 2 + i;
            int row = (f >> 1) * 16 + l15;          // s-row (K) / d-row (Vt)
            int cb  = (f & 1) * 32 + quad * 8;
            GLD(kproj + (size_t)(b * SEQ + s0 + row) * D_MODEL + h * HDIM + cb,
                Kst + f * 512);
            GLD(vt + (size_t)(b * 1024 + h * HDIM + row) * D_MODEL + s0 + cb,
                Vst + f * 512);
        }
        __syncthreads();

        floatx4 s_acc[4] = {};
        #pragma unroll
        for (int j = 0; j < 4; ++j)
            #pragma unroll
            for (int kk = 0; kk < 2; ++kk) {
                bf16x8 kf = *(const bf16x8*)&Kst[(j * 2 + kk) * 512 + lane * 8];
                s_acc[j] = __builtin_amdgcn_mfma_f32_16x16x32_bf16(
                    qf[kk], kf, s_acc[j], 0, 0, 0);
            }

        #pragma unroll
        for (int j = 0; j < 4; ++j) {
            float mb = MB[s0 + j * 16 + l15];
            #pragma unroll
            for (int r = 0; r < 4; ++r) {
                float p = __builtin_amdgcn_exp2f(fmaf(s_acc[j][r], SC2, mb));
                Past[pbase + (j >> 1) * 512 + (j & 1) * 256 + r * 8] = (bf16)p;
            }
        }
        __builtin_amdgcn_wave_barrier();

        bf16x8 pf[2];
        #pragma unroll
        for (int kk = 0; kk < 2; ++kk)
            pf[kk] = *(const bf16x8*)&Past[w * 1024 + kk * 512 + lane * 8];

        #pragma unroll
        for (int kk = 0; kk < 2; ++kk)
            accl = __builtin_amdgcn_mfma_f32_16x16x32_bf16(pf[kk], ones, accl,
                                                           0, 0, 0);
        #pragma unroll
        for (int j = 0; j < 4; ++j)
            #pragma unroll
            for (int kk = 0; kk < 2; ++kk) {
                bf16x8 vf = *(const bf16x8*)&Vst[(j * 2 + kk) * 512 + lane * 8];
                o[j] = __builtin_amdgcn_mfma_f32_16x16x32_bf16(
                    pf[kk], vf, o[j], 0, 0, 0);
            }
    }

    float inv[4];
    #pragma unroll
    for (int r = 0; r < 4; ++r) inv[r] = (accl[r] > 0.f) ? 1.f / accl[r] : 0.f;
    #pragma unroll
    for (int j = 0; j < 4; ++j)
        #pragma unroll
        for (int r = 0; r < 4; ++r) {
            int row = q0 + w * 16 + quad * 4 + r;
            int col = h * HDIM + j * 16 + l15;
            ctx[(size_t)(b * SEQ + row) * D_MODEL + col] = (bf16)(o[j][r] * inv[r]);
        }
}

// ---------------------------------------------------------------------------
extern "C" void kernel_launch(void* const* d_in, const int* in_sizes, int n_in,
                              void* d_out, int out_size, void* d_ws, size_t ws_size,
                              hipStream_t stream)
{
    // ws: [0,16K) mbias fp32 | [64K,+32MB) converted bf16 (q,k,v,Wq,Wk,Wv,Wo)
    //     | qproj 8MB | kproj 8MB | vt 8MB | ctx 8MB.   Total ~64.1MB.
    char* wsb = (char*)d_ws;
    float* mbias = (float*)wsb;
    bf16* cbase = (bf16*)(wsb + 65536);
    bf16 *cq = cbase, *ck = cq + ACT_N, *cv = ck + ACT_N;
    bf16 *cWq = cv + ACT_N, *cWk = cWq + W_N, *cWv = cWk + W_N, *cWo = cWv + W_N;
    bf16* qproj = cWo + W_N;
    bf16* kproj = qproj + ACT_N;
    bf16* vt    = kproj + ACT_N;
    bf16* ctx   = vt + ACT_N;
    float* out  = (float*)d_out;

    k_convert_all<<<8193, 256, 0, stream>>>(
        (const float*)d_in[0], (const float*)d_in[1], (const float*)d_in[2],
        (const float*)d_in[4], (const float*)d_in[6], (const float*)d_in[8],
        (const float*)d_in[10], cbase, (const unsigned*)d_in[3], mbias);

    k_gemm_proj<<<768, 256, 0, stream>>>(cq, ck, cv, cWq, cWk, cWv,
                                         (const float*)d_in[5],
                                         (const float*)d_in[7],
                                         (const float*)d_in[9],
                                         qproj, kproj, vt);
    k_attn<<<dim3(16, 64), 256, 0, stream>>>(qproj, kproj, vt, mbias, ctx);
    k_gemm_o<<<dim3(8, 32), 256, 0, stream>>>(ctx, cWo, (const float*)d_in[11], out);
}

// Round 10
// 230.829 us; speedup vs baseline: 1.1343x; 1.1343x over previous
//
#include <hip/hip_runtime.h>
#include <hip/hip_bf16.h>

// B=4, L=S=1024, D=1024, H=16, HD=64. Inputs fp32, output fp32, mask bool-ish
// (runtime-classified). History: R7 241us (proj 56us @1.90TB/s, 3.1e6 LDS
// conflicts). R8 BK=64: 68us. R9 fragment-ordered staging: 74us @1.45TB/s —
// GLD coalescing needs LANE-adjacent global addresses; frag order scatters
// lanes 2KB apart (64x16B vs 16x64B transactions). R10: R7 gemm_core verbatim
// + XCD-aware swizzles (proj pairs, o-proj pairs, attn grid swap) to cut the
// 80MB-vs-31MB A/W/KV overfetch from per-XCD L2 misses.

typedef __bf16 bf16;
typedef __bf16 bf16x8 __attribute__((ext_vector_type(8)));
typedef float floatx4 __attribute__((ext_vector_type(4)));

#define D_MODEL 1024
#define NHEAD   16
#define HDIM    64
#define BATCH   4
#define SEQ     1024
#define M_ROWS  (BATCH * SEQ)         // 4096
#define ACT_N   ((size_t)M_ROWS * D_MODEL)    // 4M
#define W_N     ((size_t)D_MODEL * D_MODEL)   // 1M
#define SC2     0.18033688011112042f  // 0.125 * log2(e)

#define GLD(gp, lp) __builtin_amdgcn_global_load_lds( \
    (__attribute__((address_space(1))) void*)(gp), \
    (__attribute__((address_space(3))) void*)(lp), 16, 0, 0)

// ---------------------------------------------------------------------------
// Fused convert + mask. Blocks 0..8191: fp32->bf16 of q,k,v,Wq,Wk,Wv,Wo into
// one contiguous bf16 region (8 elems/thread). Block 8192: classify mask
// dtype (int32/byte/bf16/fp32) and emit float bias 0 / -1e30.
// ---------------------------------------------------------------------------
__global__ __launch_bounds__(256)
void k_convert_all(const float* __restrict__ a0, const float* __restrict__ a1,
                   const float* __restrict__ a2,
                   const float* __restrict__ w0, const float* __restrict__ w1,
                   const float* __restrict__ w2, const float* __restrict__ w3,
                   bf16* __restrict__ dst,
                   const unsigned* __restrict__ m, float* __restrict__ mbias)
{
    if (blockIdx.x == 8192) {
        __shared__ unsigned viol[4];
        __shared__ int fmsh;
        if (threadIdx.x < 4) viol[threadIdx.x] = 0;
        __syncthreads();
        unsigned a = 0, b = 0, c = 0, d = 0;
        for (int i = threadIdx.x; i < 1024; i += 256) {
            unsigned v = m[i];
            if (v > 1u) a = 1;
            if (((v & 0xFFu) > 1u) || (((v >> 8) & 0xFFu) > 1u) ||
                (((v >> 16) & 0xFFu) > 1u) || (((v >> 24) & 0xFFu) > 1u)) b = 1;
            unsigned lo = v & 0xFFFFu, hi = v >> 16;
            if (!((lo == 0u || lo == 0x3F80u) && (hi == 0u || hi == 0x3F80u))) c = 1;
            if (lo != 0u) d = 1;
        }
        if (a) atomicOr(&viol[0], 1u);
        if (b) atomicOr(&viol[1], 1u);
        if (c) atomicOr(&viol[2], 1u);
        if (d) atomicOr(&viol[3], 1u);
        __syncthreads();
        if (threadIdx.x == 0) {
            int fm;
            if (!viol[0])      fm = 1;
            else if (!viol[1]) fm = 0;
            else if (!viol[2]) fm = viol[3] ? 2 : 3;
            else               fm = 0;
            fmsh = fm;
        }
        __syncthreads();
        const int fm = fmsh;
        for (int i = 0; i < 16; ++i) {
            int s = i * 256 + threadIdx.x;
            bool msk;
            if (fm == 1)      msk = ((const int*)m)[s] != 0;
            else if (fm == 2) msk = ((const unsigned short*)m)[s] != 0;
            else if (fm == 3) msk = ((const unsigned*)m)[s] != 0;
            else              msk = ((const unsigned char*)m)[s] != 0;
            mbias[s] = msk ? -1e30f : 0.f;
        }
        return;
    }

    size_t i = ((size_t)blockIdx.x * 256 + threadIdx.x) * 8;
    const float* src; size_t off;
    if (i < ((size_t)12 << 20)) {
        int z = (int)(i >> 22);
        src = (z == 0) ? a0 : (z == 1) ? a1 : a2;
        off = i & (((size_t)1 << 22) - 1);
    } else {
        size_t r = i - ((size_t)12 << 20);
        int j = (int)(r >> 20);
        src = (j == 0) ? w0 : (j == 1) ? w1 : (j == 2) ? w2 : w3;
        off = r & (((size_t)1 << 20) - 1);
    }
    float4 f0 = ((const float4*)(src + off))[0];
    float4 f1 = ((const float4*)(src + off))[1];
    bf16x8 o;
    o[0] = (bf16)f0.x; o[1] = (bf16)f0.y; o[2] = (bf16)f0.z; o[3] = (bf16)f0.w;
    o[4] = (bf16)f1.x; o[5] = (bf16)f1.y; o[6] = (bf16)f1.z; o[7] = (bf16)f1.w;
    *(bf16x8*)(dst + i) = o;
}

// ---------------------------------------------------------------------------
// GEMM core (R7-verbatim): C[m0..+128, n0..+128] = A@W^T + bias. BK=32,
// row-major staging (lane-contiguous global reads: 16 rows x 64B per GLD).
// ---------------------------------------------------------------------------
template<typename CT>
__device__ __forceinline__ void gemm_core(const bf16* __restrict__ A,
                                          const bf16* __restrict__ W,
                                          const float* __restrict__ bias,
                                          CT* __restrict__ C,
                                          int m0, int n0, bool rowBias)
{
    __shared__ alignas(16) bf16 As[128 * 32];
    __shared__ alignas(16) bf16 Bs[128 * 32];

    const int t    = threadIdx.x;
    const int lane = t & 63;
    const int w    = t >> 6;
    const int wm   = w >> 1, wn = w & 1;
    const int l15  = lane & 15;
    const int quad = lane >> 4;

    floatx4 acc[4][4] = {};

    for (int k0 = 0; k0 < D_MODEL; k0 += 32) {
        #pragma unroll
        for (int i = 0; i < 2; ++i) {
            int c   = i * 256 + t;
            int row = c >> 2, cb = (c & 3) * 8;
            const bf16* ga = A + (size_t)(m0 + row) * D_MODEL + k0 + cb;
            const bf16* gb = W + (size_t)(n0 + row) * D_MODEL + k0 + cb;
            int lo = (i * 256 + w * 64) * 8;   // wave-uniform base (+lane*16)
            GLD(ga, As + lo);
            GLD(gb, Bs + lo);
        }
        __syncthreads();

        bf16x8 af[4], bfr[4];
        #pragma unroll
        for (int i = 0; i < 4; ++i)
            af[i] = *(const bf16x8*)&As[(wm * 64 + i * 16 + l15) * 32 + quad * 8];
        #pragma unroll
        for (int j = 0; j < 4; ++j)
            bfr[j] = *(const bf16x8*)&Bs[(wn * 64 + j * 16 + l15) * 32 + quad * 8];

        #pragma unroll
        for (int i = 0; i < 4; ++i)
            #pragma unroll
            for (int j = 0; j < 4; ++j)
                acc[i][j] = __builtin_amdgcn_mfma_f32_16x16x32_bf16(
                    af[i], bfr[j], acc[i][j], 0, 0, 0);
        __syncthreads();
    }

    // epilogue: C/D layout col=lane&15, row=quad*4+r
    #pragma unroll
    for (int i = 0; i < 4; ++i) {
        int rowb = m0 + wm * 64 + i * 16 + quad * 4;
        float bvr[4];
        if (rowBias) {
            #pragma unroll
            for (int r = 0; r < 4; ++r) bvr[r] = bias[rowb + r];
        }
        #pragma unroll
        for (int j = 0; j < 4; ++j) {
            int col = n0 + wn * 64 + j * 16 + l15;
            float bc = rowBias ? 0.f : bias[col];
            #pragma unroll
            for (int r = 0; r < 4; ++r) {
                float val = acc[i][j][r] + (rowBias ? bvr[r] : bc);
                C[(size_t)(rowb + r) * D_MODEL + col] = (CT)val;
            }
        }
    }
}

// ---------------------------------------------------------------------------
// Fused projection GEMM, XCD-swizzled. 768 blocks; HW round-robins blockIdx
// across 8 XCDs (bid&7). Pair p = (z,m)-slice; its 8 n-blocks all carry the
// same bid&7 -> same XCD -> A-slice fetched once, W (2MB) stays L2-resident.
// p<32: Q-proj m=p. p<64: K-proj m=p-32. p>=64: V-proj transposed per batch
// (Vt_b = Wv @ value_b^T + bv by row), batch=(p-64)>>3, m=(p-64)&7.
// ---------------------------------------------------------------------------
__global__ __launch_bounds__(256)
void k_gemm_proj(const bf16* __restrict__ cq, const bf16* __restrict__ ck,
                 const bf16* __restrict__ cv,
                 const bf16* __restrict__ cWq, const bf16* __restrict__ cWk,
                 const bf16* __restrict__ cWv,
                 const float* __restrict__ bq, const float* __restrict__ bk,
                 const float* __restrict__ bv,
                 bf16* __restrict__ qproj, bf16* __restrict__ kproj,
                 bf16* __restrict__ vt)
{
    const int bid = blockIdx.x;
    const int x = bid & 7;            // XCD
    const int j = bid >> 3;           // 0..95
    const int p = x * 12 + (j >> 3);  // pair 0..95
    const int n0 = (j & 7) * 128;
    if (p < 64) {
        int z = p >> 5, m0 = (p & 31) * 128;
        gemm_core<bf16>(z ? ck : cq, z ? cWk : cWq, z ? bk : bq,
                        z ? kproj : qproj, m0, n0, false);
    } else {
        int pv = p - 64;
        int b = pv >> 3, m0 = (pv & 7) * 128;
        gemm_core<bf16>(cWv, cv + (size_t)b * W_N, bv,
                        vt + (size_t)b * W_N, m0, n0, true);
    }
}

// O-projection, XCD-swizzled: 256 blocks, 32 m-pairs x 8 n.
__global__ __launch_bounds__(256)
void k_gemm_o(const bf16* __restrict__ A, const bf16* __restrict__ W,
              const float* __restrict__ bb, float* __restrict__ C)
{
    const int bid = blockIdx.x;
    const int x = bid & 7;
    const int j = bid >> 3;           // 0..31
    const int p = x * 4 + (j >> 3);   // m-pair 0..31
    const int n0 = (j & 7) * 128;
    gemm_core<float>(A, W, bb, C, p * 128, n0, false);
}

// ---------------------------------------------------------------------------
// Flash attention, fragment-ordered LDS. Grid (B*H, L/64) — bh on x so all 16
// q-tiles of one (b,h) share an XCD (K/V head-slice fetched once per XCD).
// 256 thr (4 waves), wave = 16 q rows. No-max exp2 softmax; l via MFMA with
// ones-B-fragment.
// ---------------------------------------------------------------------------
__global__ __launch_bounds__(256)
void k_attn(const bf16* __restrict__ qproj, const bf16* __restrict__ kproj,
            const bf16* __restrict__ vt, const float* __restrict__ mbias_g,
            bf16* __restrict__ ctx)
{
    __shared__ alignas(16) bf16 Qst[4096];   // [w*2+kk][lane]*8, frag order
    __shared__ alignas(16) bf16 Kst[4096];   // [f=j*2+kk][lane]*8
    __shared__ alignas(16) bf16 Vst[4096];
    __shared__ alignas(16) bf16 Past[4096];  // per-wave 1024, A-frag order
    __shared__ float MB[1024];

    const int t    = threadIdx.x;
    const int lane = t & 63;
    const int w    = t >> 6;
    const int l15  = lane & 15;
    const int quad = lane >> 4;

    const int b  = blockIdx.x >> 4;
    const int h  = blockIdx.x & 15;
    const int q0 = blockIdx.y * 64;

    #pragma unroll
    for (int i = 0; i < 4; ++i)
        MB[i * 256 + t] = mbias_g[b * SEQ + i * 256 + t];

    #pragma unroll
    for (int kk = 0; kk < 2; ++kk) {
        const bf16* gp = qproj + (size_t)(b * SEQ + q0 + w * 16 + l15) * D_MODEL
                       + h * HDIM + kk * 32 + quad * 8;
        GLD(gp, Qst + (w * 2 + kk) * 512);
    }
    __syncthreads();

    bf16x8 qf[2];
    #pragma unroll
    for (int kk = 0; kk < 2; ++kk)
        qf[kk] = *(const bf16x8*)&Qst[(w * 2 + kk) * 512 + lane * 8];

    bf16x8 ones;
    #pragma unroll
    for (int e = 0; e < 8; ++e) ones[e] = (bf16)1.0f;

    floatx4 o[4] = {};
    floatx4 accl = {};

    const int pbase = w * 1024 + (l15 >> 3) * 128 + quad * 32 + (l15 & 7);

    for (int s0 = 0; s0 < SEQ; s0 += 64) {
        __syncthreads();
        #pragma unroll
        for (int i = 0; i < 2; ++i) {
            int f = w * 2 + i;
            int row = (f >> 1) * 16 + l15;          // s-row (K) / d-row (Vt)
            int cb  = (f & 1) * 32 + quad * 8;
            GLD(kproj + (size_t)(b * SEQ + s0 + row) * D_MODEL + h * HDIM + cb,
                Kst + f * 512);
            GLD(vt + (size_t)(b * 1024 + h * HDIM + row) * D_MODEL + s0 + cb,
                Vst + f * 512);
        }
        __syncthreads();

        floatx4 s_acc[4] = {};
        #pragma unroll
        for (int j = 0; j < 4; ++j)
            #pragma unroll
            for (int kk = 0; kk < 2; ++kk) {
                bf16x8 kf = *(const bf16x8*)&Kst[(j * 2 + kk) * 512 + lane * 8];
                s_acc[j] = __builtin_amdgcn_mfma_f32_16x16x32_bf16(
                    qf[kk], kf, s_acc[j], 0, 0, 0);
            }

        #pragma unroll
        for (int j = 0; j < 4; ++j) {
            float mb = MB[s0 + j * 16 + l15];
            #pragma unroll
            for (int r = 0; r < 4; ++r) {
                float p = __builtin_amdgcn_exp2f(fmaf(s_acc[j][r], SC2, mb));
                Past[pbase + (j >> 1) * 512 + (j & 1) * 256 + r * 8] = (bf16)p;
            }
        }
        __builtin_amdgcn_wave_barrier();

        bf16x8 pf[2];
        #pragma unroll
        for (int kk = 0; kk < 2; ++kk)
            pf[kk] = *(const bf16x8*)&Past[w * 1024 + kk * 512 + lane * 8];

        #pragma unroll
        for (int kk = 0; kk < 2; ++kk)
            accl = __builtin_amdgcn_mfma_f32_16x16x32_bf16(pf[kk], ones, accl,
                                                           0, 0, 0);
        #pragma unroll
        for (int j = 0; j < 4; ++j)
            #pragma unroll
            for (int kk = 0; kk < 2; ++kk) {
                bf16x8 vf = *(const bf16x8*)&Vst[(j * 2 + kk) * 512 + lane * 8];
                o[j] = __builtin_amdgcn_mfma_f32_16x16x32_bf16(
                    pf[kk], vf, o[j], 0, 0, 0);
            }
    }

    float inv[4];
    #pragma unroll
    for (int r = 0; r < 4; ++r) inv[r] = (accl[r] > 0.f) ? 1.f / accl[r] : 0.f;
    #pragma unroll
    for (int j = 0; j < 4; ++j)
        #pragma unroll
        for (int r = 0; r < 4; ++r) {
            int row = q0 + w * 16 + quad * 4 + r;
            int col = h * HDIM + j * 16 + l15;
            ctx[(size_t)(b * SEQ + row) * D_MODEL + col] = (bf16)(o[j][r] * inv[r]);
        }
}

// ---------------------------------------------------------------------------
extern "C" void kernel_launch(void* const* d_in, const int* in_sizes, int n_in,
                              void* d_out, int out_size, void* d_ws, size_t ws_size,
                              hipStream_t stream)
{
    // ws: [0,16K) mbias fp32 | [64K,+32MB) converted bf16 (q,k,v,Wq,Wk,Wv,Wo)
    //     | qproj 8MB | kproj 8MB | vt 8MB | ctx 8MB.   Total ~64.1MB.
    char* wsb = (char*)d_ws;
    float* mbias = (float*)wsb;
    bf16* cbase = (bf16*)(wsb + 65536);
    bf16 *cq = cbase, *ck = cq + ACT_N, *cv = ck + ACT_N;
    bf16 *cWq = cv + ACT_N, *cWk = cWq + W_N, *cWv = cWk + W_N, *cWo = cWv + W_N;
    bf16* qproj = cWo + W_N;
    bf16* kproj = qproj + ACT_N;
    bf16* vt    = kproj + ACT_N;
    bf16* ctx   = vt + ACT_N;
    float* out  = (float*)d_out;

    k_convert_all<<<8193, 256, 0, stream>>>(
        (const float*)d_in[0], (const float*)d_in[1], (const float*)d_in[2],
        (const float*)d_in[4], (const float*)d_in[6], (const float*)d_in[8],
        (const float*)d_in[10], cbase, (const unsigned*)d_in[3], mbias);

    k_gemm_proj<<<768, 256, 0, stream>>>(cq, ck, cv, cWq, cWk, cWv,
                                         (const float*)d_in[5],
                                         (const float*)d_in[7],
                                         (const float*)d_in[9],
                                         qproj, kproj, vt);
    k_attn<<<dim3(64, 16), 256, 0, stream>>>(qproj, kproj, vt, mbias, ctx);
    k_gemm_o<<<256, 256, 0, stream>>>(ctx, cWo, (const float*)d_in[11], out);
}